// Round 4
// baseline (162.671 us; speedup 1.0000x reference)
//
#include <hip/hip_runtime.h>

// Fused CRF NLL: B=1024, T=2048, K=9 (START=7, STOP=8).
// One block per sentence (256 thr = 32 chunk-groups x 8 lanes).
// Phase 1: gold score, data-parallel, unrolled-8 loads.
// Phase 2: per-chunk 7x7 linear-space transfer matrix, 1 lane per column.
//   - E in SGPRs (readfirstlane)
//   - each lane loads the full 9-float feat row (2x float4, L1 broadcast
//     across the 7 lanes of its group) and computes its own 7 exps.
//     NO DS ops in the inner loop (the per-CU LDS pipe was the R3 bottleneck).
//   - 4-step software pipeline; exps computed at prefetch time (ef buffers),
//     so the recurrence critical path is 7 FMA + 1 mul per step.
//   - renorm every 4 steps (growth in [e^-35, 1e14], fp32-safe)
// Phase 3: threads 0..7 fold 32 log-matrices from LDS, STOP readout,
//   atomicAdd((fwd-gold)/B).

#define START_TAG 7
#define STOP_TAG  8
#define KDIM      9
#define NS        7
#define CHUNKS    32
#define NEGINF    (-1e30f)

__device__ __forceinline__ float rfl(float x) {
    return __int_as_float(__builtin_amdgcn_readfirstlane(__float_as_int(x)));
}

__global__ __launch_bounds__(256) void crf_fused_kernel(
    const float* __restrict__ feats,
    const float* __restrict__ trans,
    const int*   __restrict__ tags,
    const int*   __restrict__ lengths,
    float* __restrict__ out,
    int B, int T, int L)
{
    __shared__ float s_trans[81];
    __shared__ float s_E[49];
    __shared__ float s_M[CHUNKS * 64];   // [c][j*8 + i] rows padded to 8
    __shared__ float s_gold[4];

    const int tid = threadIdx.x;
    const int b   = blockIdx.x;

    if (tid < 81) s_trans[tid] = trans[tid];
    if (tid >= 128 && tid < 177) {
        int k = tid - 128;
        s_E[k] = __expf(trans[(k / 7) * 9 + (k % 7)]);
    }
    __syncthreads();

    const int    len   = lengths[b];
    const int*   tg    = tags  + (size_t)b * T;
    const float* fbase = feats + (size_t)b * T * KDIM;

    // ---------------- phase 1: gold score ----------------
    {
        int per = (T >> 8) > 0 ? (T >> 8) : 1;
        int t0  = tid * per;
        float g = 0.f;
        if (t0 < len) {
            int te   = min(t0 + per, len);
            int prev = (t0 == 0) ? START_TAG : tg[t0 - 1];
            if (per == 8) {
                #pragma unroll
                for (int k = 0; k < 8; ++k) {
                    int t   = t0 + k;
                    int tc  = min(t, te - 1);
                    int cur = tg[tc];
                    float v = s_trans[cur * 9 + prev] + fbase[(size_t)tc * KDIM + cur];
                    g += (t < te) ? v : 0.f;
                    prev = cur;
                }
            } else {
                for (int k = 0; k < per; ++k) {
                    int t   = t0 + k;
                    int tc  = min(t, te - 1);
                    int cur = tg[tc];
                    float v = s_trans[cur * 9 + prev] + fbase[(size_t)tc * KDIM + cur];
                    g += (t < te) ? v : 0.f;
                    prev = cur;
                }
            }
            if (len - 1 >= t0 && len - 1 < t0 + per)
                g += s_trans[STOP_TAG * 9 + tg[len - 1]];
        }
        #pragma unroll
        for (int off = 32; off > 0; off >>= 1) g += __shfl_xor(g, off, 64);
        if ((tid & 63) == 0) s_gold[tid >> 6] = g;
    }

    // ---------------- phase 2: chunk matrices ----------------
    {
        const int lane8  = tid & 7;
        const int c      = tid >> 3;
        const int t0     = c * L;
        const int tstart = max(t0, 1);
        const int tend   = min(t0 + L, len);

        if (lane8 < NS) {
            float* Mw = s_M + c * 64;
            if (tstart < tend) {
                float E[49];
                #pragma unroll
                for (int k = 0; k < 49; ++k) E[k] = rfl(s_E[k]);

                float p[NS];
                #pragma unroll
                for (int j = 0; j < NS; ++j) p[j] = (j == lane8) ? 1.f : 0.f;
                float s = 0.f;
                int rem = tend - tstart;

                const float* fp = fbase + (size_t)tstart * KDIM;
                float ef0[NS], ef1[NS], ef2[NS], ef3[NS];

                #define EXP8(EF, A, B) do {                                     \
                    (EF)[0] = __expf((A).x); (EF)[1] = __expf((A).y);           \
                    (EF)[2] = __expf((A).z); (EF)[3] = __expf((A).w);           \
                    (EF)[4] = __expf((B).x); (EF)[5] = __expf((B).y);           \
                    (EF)[6] = __expf((B).z);                                    \
                } while (0)

                #define CRF_STEP(EF) do {                                       \
                    float q[NS];                                                \
                    _Pragma("unroll")                                           \
                    for (int j = 0; j < NS; ++j) {                              \
                        float acc = E[j * 7] * p[0];                            \
                        _Pragma("unroll")                                       \
                        for (int i = 1; i < NS; ++i)                            \
                            acc = fmaf(E[j * 7 + i], p[i], acc);                \
                        q[j] = acc;                                             \
                    }                                                           \
                    _Pragma("unroll")                                           \
                    for (int j = 0; j < NS; ++j) p[j] = q[j] * (EF)[j];         \
                } while (0)

                #define CRF_RENORM() do {                                       \
                    float m = p[0];                                             \
                    _Pragma("unroll")                                           \
                    for (int j = 1; j < NS; ++j) m = fmaxf(m, p[j]);            \
                    float rm = __builtin_amdgcn_rcpf(m);                        \
                    _Pragma("unroll")                                           \
                    for (int j = 0; j < NS; ++j) p[j] *= rm;                    \
                    s += __logf(m);                                             \
                } while (0)

                // initial clamped preload of rows tstart..tstart+3
                {
                    int o1 = KDIM * min(1, rem - 1);
                    int o2 = KDIM * min(2, rem - 1);
                    int o3 = KDIM * min(3, rem - 1);
                    float4 A0 = *(const float4*)(fp);
                    float4 B0 = *(const float4*)(fp + 4);
                    float4 A1 = *(const float4*)(fp + o1);
                    float4 B1 = *(const float4*)(fp + o1 + 4);
                    float4 A2 = *(const float4*)(fp + o2);
                    float4 B2 = *(const float4*)(fp + o2 + 4);
                    float4 A3 = *(const float4*)(fp + o3);
                    float4 B3 = *(const float4*)(fp + o3 + 4);
                    EXP8(ef0, A0, B0); EXP8(ef1, A1, B1);
                    EXP8(ef2, A2, B2); EXP8(ef3, A3, B3);
                }
                fp += 4 * KDIM;

                while (rem >= 8) {
                    float4 A0 = *(const float4*)(fp);
                    float4 B0 = *(const float4*)(fp + 4);
                    float4 A1 = *(const float4*)(fp + KDIM);
                    float4 B1 = *(const float4*)(fp + KDIM + 4);
                    float4 A2 = *(const float4*)(fp + 2 * KDIM);
                    float4 B2 = *(const float4*)(fp + 2 * KDIM + 4);
                    float4 A3 = *(const float4*)(fp + 3 * KDIM);
                    float4 B3 = *(const float4*)(fp + 3 * KDIM + 4);
                    fp += 4 * KDIM;
                    CRF_STEP(ef0); CRF_STEP(ef1); CRF_STEP(ef2); CRF_STEP(ef3);
                    CRF_RENORM();
                    EXP8(ef0, A0, B0); EXP8(ef1, A1, B1);
                    EXP8(ef2, A2, B2); EXP8(ef3, A3, B3);
                    rem -= 4;
                }
                if (rem > 4) {
                    int e1 = KDIM * min(1, rem - 5);
                    int e2 = KDIM * min(2, rem - 5);
                    float4 A0 = *(const float4*)(fp);
                    float4 B0 = *(const float4*)(fp + 4);
                    float4 A1 = *(const float4*)(fp + e1);
                    float4 B1 = *(const float4*)(fp + e1 + 4);
                    float4 A2 = *(const float4*)(fp + e2);
                    float4 B2 = *(const float4*)(fp + e2 + 4);
                    CRF_STEP(ef0); CRF_STEP(ef1); CRF_STEP(ef2); CRF_STEP(ef3);
                    CRF_RENORM();
                    EXP8(ef0, A0, B0); EXP8(ef1, A1, B1); EXP8(ef2, A2, B2);
                    rem -= 4;
                }
                // rem in [1,4]
                CRF_STEP(ef0);
                if (rem > 1) CRF_STEP(ef1);
                if (rem > 2) CRF_STEP(ef2);
                if (rem > 3) CRF_STEP(ef3);
                CRF_RENORM();

                #pragma unroll
                for (int j = 0; j < NS; ++j)
                    Mw[j * 8 + lane8] = __logf(p[j]) + s;
                #undef CRF_STEP
                #undef CRF_RENORM
                #undef EXP8
            } else {
                #pragma unroll
                for (int j = 0; j < NS; ++j)
                    Mw[j * 8 + lane8] = (j == lane8) ? 0.f : NEGINF;
            }
        }
    }
    __syncthreads();

    // ---------------- phase 3: fold + output ----------------
    if (tid < 8) {
        const int  lane  = tid;
        const bool isrow = (lane < NS);
        const int  row   = isrow ? lane : 0;

        float a, S;
        {
            float a0 = isrow ? (s_trans[lane * 9 + START_TAG] + fbase[lane]) : NEGINF;
            float m = a0;
            #pragma unroll
            for (int off = 4; off > 0; off >>= 1) m = fmaxf(m, __shfl_xor(m, off, 8));
            a = a0 - m;
            S = m;
        }

        const int nc = min(CHUNKS, (len + L - 1) / L);
        const float* Mr0 = s_M + row * 8;
        float4 mA = *(const float4*)(Mr0);
        float4 mB = *(const float4*)(Mr0 + 4);
        for (int c = 0; c < nc; ++c) {
            int cn = min(c + 1, CHUNKS - 1);
            float4 nA = *(const float4*)(Mr0 + cn * 64);
            float4 nB = *(const float4*)(Mr0 + cn * 64 + 4);
            float tv[NS] = { mA.x, mA.y, mA.z, mA.w, mB.x, mB.y, mB.z };
            float tm = NEGINF;
            #pragma unroll
            for (int i = 0; i < NS; ++i) {
                tv[i] += __shfl(a, i, 8);
                tm = fmaxf(tm, tv[i]);
            }
            float sum = 0.f;
            #pragma unroll
            for (int i = 0; i < NS; ++i) sum += __expf(tv[i] - tm);
            float na = isrow ? (tm + __logf(sum)) : NEGINF;
            float m2 = na;
            #pragma unroll
            for (int off = 4; off > 0; off >>= 1) m2 = fmaxf(m2, __shfl_xor(m2, off, 8));
            a = na - m2;
            S += m2;
            mA = nA; mB = nB;
        }

        float term = isrow ? (a + s_trans[STOP_TAG * 9 + lane]) : NEGINF;
        float tm2 = term;
        #pragma unroll
        for (int off = 4; off > 0; off >>= 1) tm2 = fmaxf(tm2, __shfl_xor(tm2, off, 8));
        float e = isrow ? __expf(term - tm2) : 0.f;
        #pragma unroll
        for (int off = 4; off > 0; off >>= 1) e += __shfl_xor(e, off, 8);

        if (lane == 0) {
            float fwd = S + tm2 + __logf(e);
            float g = s_gold[0] + s_gold[1] + s_gold[2] + s_gold[3];
            atomicAdd(out, (fwd - g) * (1.0f / (float)B));
        }
    }
}

__global__ void init_out_kernel(float* out) {
    if (threadIdx.x == 0) out[0] = 0.f;
}

extern "C" void kernel_launch(void* const* d_in, const int* in_sizes, int n_in,
                              void* d_out, int out_size, void* d_ws, size_t ws_size,
                              hipStream_t stream) {
    const float* feats   = (const float*)d_in[0];
    const float* trans   = (const float*)d_in[1];
    const int*   tags    = (const int*)d_in[2];
    const int*   lengths = (const int*)d_in[3];

    int B = in_sizes[3];
    int T = in_sizes[2] / B;
    int L = (T + CHUNKS - 1) / CHUNKS;   // 64 for T=2048

    init_out_kernel<<<1, 64, 0, stream>>>((float*)d_out);
    crf_fused_kernel<<<B, 256, 0, stream>>>(
        feats, trans, tags, lengths, (float*)d_out, B, T, L);
}